// Round 1
// baseline (485.451 us; speedup 1.0000x reference)
//
#include <hip/hip_runtime.h>
#include <stdint.h>

typedef unsigned short u16;
typedef __bf16 bf16x8 __attribute__((ext_vector_type(8)));
typedef float f32x4 __attribute__((ext_vector_type(4)));

// ---------- helpers ----------
__device__ __forceinline__ u16 f2bf(float f) {
  union { float f; uint32_t u; } v; v.f = f;
  uint32_t u = v.u;
  return (u16)((u + 0x7FFFu + ((u >> 16) & 1u)) >> 16);  // RNE
}

// async global->LDS, 16B per lane. LDS dest = wave-uniform base + lane*16.
__device__ __forceinline__ void cp16(const void* g, void* lds) {
  __builtin_amdgcn_global_load_lds(
      (const __attribute__((address_space(1))) uint32_t*)(uintptr_t)g,
      (__attribute__((address_space(3))) uint32_t*)(uint32_t)(uintptr_t)lds,
      16, 0, 0);
}

// ---------- f32 -> bf16 conversion ----------
__global__ __launch_bounds__(256) void cvt_kernel(const float* __restrict__ s,
                                                  u16* __restrict__ d, int n4) {
  int i = blockIdx.x * 256 + threadIdx.x;
  if (i >= n4) return;
  float4 f = ((const float4*)s)[i];
  uint2 p;
  p.x = (uint32_t)f2bf(f.x) | ((uint32_t)f2bf(f.y) << 16);
  p.y = (uint32_t)f2bf(f.z) | ((uint32_t)f2bf(f.w) << 16);
  ((uint2*)d)[i] = p;
}

// ---------- shared 128x128 GEMM mainloop (A[M,K] x Bt[N,K], bf16, K%64==0) ----------
// block = 256 threads (4 waves, 2x2 wave grid, 64x64 per wave, 4x4 MFMA tiles).
// LDS tiles As/Bs: [128 rows][64 u16], XOR-swizzled in 16B chunks: slot j holds
// global chunk j^(row&7).
__device__ __forceinline__ void gemm128(const u16* __restrict__ A,
                                        const u16* __restrict__ Bt,
                                        int m0, int n0, int K,
                                        u16* As, u16* Bs, f32x4 acc[4][4]) {
  const int tid = threadIdx.x;
  const int l = tid & 63, w = tid >> 6;
  const int wr = w >> 1, wc = w & 1;
  const int quad = l >> 4, c = l & 15;
  const f32x4 zero = {0.f, 0.f, 0.f, 0.f};
  for (int i = 0; i < 4; ++i)
    for (int j = 0; j < 4; ++j) acc[i][j] = zero;

  for (int k0 = 0; k0 < K; k0 += 64) {
    __syncthreads();  // previous iter's LDS reads done
#pragma unroll
    for (int p = 0; p < 4; ++p) {
      int q = p * 256 + tid;          // chunk id 0..1023
      int row = q >> 3;
      int jj = (q & 7) ^ (row & 7);   // swizzled source column-chunk
      int ldsbase = (p * 256 + (tid & ~63)) * 8;  // wave-uniform, u16 units
      cp16(A + (size_t)(m0 + row) * K + k0 + jj * 8, As + ldsbase);
      cp16(Bt + (size_t)(n0 + row) * K + k0 + jj * 8, Bs + ldsbase);
    }
    __syncthreads();  // drains vmcnt -> tiles visible
#pragma unroll
    for (int kk = 0; kk < 2; ++kk) {
      bf16x8 af[4], bf[4];
#pragma unroll
      for (int mt = 0; mt < 4; ++mt) {
        int row = wr * 64 + mt * 16 + c;
        af[mt] = *(const bf16x8*)(As + row * 64 + ((((kk << 2) + quad)) ^ (c & 7)) * 8);
      }
#pragma unroll
      for (int nt = 0; nt < 4; ++nt) {
        int row = wc * 64 + nt * 16 + c;
        bf[nt] = *(const bf16x8*)(Bs + row * 64 + ((((kk << 2) + quad)) ^ (c & 7)) * 8);
      }
#pragma unroll
      for (int mt = 0; mt < 4; ++mt)
#pragma unroll
        for (int nt = 0; nt < 4; ++nt)
          acc[mt][nt] = __builtin_amdgcn_mfma_f32_16x16x32_bf16(
              af[mt], bf[nt], acc[mt][nt], 0, 0, 0);
    }
  }
}

// ---------- QKV projection: X[4096,1024] @ W^T + b, scatter to [bh][t][d] ----------
__global__ __launch_bounds__(256, 2) void proj_kernel(
    const u16* __restrict__ X, const u16* __restrict__ Win,
    const float* __restrict__ in_bias, u16* __restrict__ Q,
    u16* __restrict__ Kp, u16* __restrict__ Vtmp) {
  __shared__ u16 As[8192], Bs[8192];
  const int which = blockIdx.z;
  const u16* A = X + (size_t)which * (4096 * 1024);
  const u16* Bt = Win + (size_t)which * (1024 * 1024);
  const int m0 = blockIdx.y * 128, n0 = blockIdx.x * 128;
  f32x4 acc[4][4];
  gemm128(A, Bt, m0, n0, 1024, As, Bs, acc);

  u16* dst = (which == 0) ? Q : ((which == 1) ? Kp : Vtmp);
  const float scale = (which == 0) ? 0.03125f : 1.0f;  // q /= sqrt(1024)
  const float* bias = in_bias + which * 1024;
  const int l = threadIdx.x & 63, w = threadIdx.x >> 6;
  const int wr = w >> 1, wc = w & 1, quad = l >> 4, c = l & 15;
#pragma unroll
  for (int mt = 0; mt < 4; ++mt)
#pragma unroll
    for (int nt = 0; nt < 4; ++nt) {
      int n = n0 + wc * 64 + nt * 16 + c;
      float bv = bias[n];
      int h = n >> 6, d = n & 63;
#pragma unroll
      for (int r = 0; r < 4; ++r) {
        int m = m0 + wr * 64 + mt * 16 + quad * 4 + r;
        int t = m >> 2, b = m & 3;
        dst[((size_t)((b * 16 + h) * 1024 + t)) * 64 + d] =
            f2bf((acc[mt][nt][r] + bv) * scale);
      }
    }
}

// ---------- out projection: AO[4096,1024] @ Wout^T + b -> f32 ----------
__global__ __launch_bounds__(256, 2) void outproj_kernel(
    const u16* __restrict__ AO, const u16* __restrict__ Wout,
    const float* __restrict__ out_bias, float* __restrict__ out) {
  __shared__ u16 As[8192], Bs[8192];
  const int m0 = blockIdx.y * 128, n0 = blockIdx.x * 128;
  f32x4 acc[4][4];
  gemm128(AO, Wout, m0, n0, 1024, As, Bs, acc);
  const int l = threadIdx.x & 63, w = threadIdx.x >> 6;
  const int wr = w >> 1, wc = w & 1, quad = l >> 4, c = l & 15;
#pragma unroll
  for (int mt = 0; mt < 4; ++mt)
#pragma unroll
    for (int nt = 0; nt < 4; ++nt) {
      int n = n0 + wc * 64 + nt * 16 + c;
      float bv = out_bias[n];
#pragma unroll
      for (int r = 0; r < 4; ++r) {
        int m = m0 + wr * 64 + mt * 16 + quad * 4 + r;
        out[(size_t)m * 1024 + n] = acc[mt][nt][r] + bv;
      }
    }
}

// ---------- V transpose: Vtmp[bh][s][d] -> Vt[bh][d][s] ----------
__global__ __launch_bounds__(256) void transpose_v(const u16* __restrict__ Vtmp,
                                                   u16* __restrict__ Vt) {
  __shared__ u16 tile[64 * 72];  // [s][d] pad 72
  const int bh = blockIdx.y, s0 = blockIdx.x * 64;
  const u16* src = Vtmp + (size_t)bh * 65536;
  u16* dst = Vt + (size_t)bh * 65536;
#pragma unroll
  for (int p = 0; p < 2; ++p) {
    int q = p * 256 + threadIdx.x;
    int sl = q >> 3, dc = q & 7;
    uint4 v = *(const uint4*)(src + (size_t)(s0 + sl) * 64 + dc * 8);
    *(uint4*)&tile[sl * 72 + dc * 8] = v;
  }
  __syncthreads();
#pragma unroll
  for (int p = 0; p < 2; ++p) {
    int q = p * 256 + threadIdx.x;
    int d = q >> 3, sc = q & 7;
    u16 vals[8] __attribute__((aligned(16)));
#pragma unroll
    for (int j = 0; j < 8; ++j) vals[j] = tile[(sc * 8 + j) * 72 + d];
    *(uint4*)(dst + (size_t)d * 1024 + s0 + sc * 8) = *(const uint4*)vals;
  }
}

// ---------- fused attention: P = sigmoid(K.Q^T), O += P.V ----------
// Q-tile 128, S-tile 128. Computes S^T = K*Q^T so lanes hold 4 consecutive s.
__global__ __launch_bounds__(256, 2) void attn_kernel(
    const u16* __restrict__ Q, const u16* __restrict__ Kg,
    const u16* __restrict__ Vt, float* __restrict__ attn_out,
    u16* __restrict__ AO) {
  __shared__ u16 Qs[8192];    // [t 128][d 64], swizzle8
  __shared__ u16 U[16384];    // phase1: Ks [s 128][d 64] swizzle8 (first 8192)
                              // phase2: Ps [t 128][s 128] swizzle16
  __shared__ u16 Vts[8192];   // [d 64][s 128], swizzle16
  const int bh = blockIdx.y, t0 = blockIdx.x * 128;
  const int b = bh >> 4, h = bh & 15;
  const int tid = threadIdx.x, l = tid & 63, w = tid >> 6;
  const int quad = l >> 4, c = l & 15;
  const int wr = w >> 1, wc = w & 1;
  const u16* Qbh = Q + (size_t)bh * 65536;
  const u16* Kbh = Kg + (size_t)bh * 65536;
  const u16* Vtbh = Vt + (size_t)bh * 65536;
  float* attnb = attn_out + (size_t)bh * 1048576;

  // stage Q tile once
#pragma unroll
  for (int p = 0; p < 4; ++p) {
    int q = p * 256 + tid;
    int row = q >> 3, jj = (q & 7) ^ (row & 7);
    cp16(Qbh + (size_t)(t0 + row) * 64 + jj * 8, Qs + (p * 256 + (tid & ~63)) * 8);
  }

  const f32x4 zero = {0.f, 0.f, 0.f, 0.f};
  f32x4 acc_o[2][4];
  for (int i = 0; i < 2; ++i)
    for (int j = 0; j < 4; ++j) acc_o[i][j] = zero;

  for (int s0 = 0; s0 < 1024; s0 += 128) {
    __syncthreads();  // prev iter's U/Vts readers done
    // stage K tile into U[0:8192]
#pragma unroll
    for (int p = 0; p < 4; ++p) {
      int q = p * 256 + tid;
      int row = q >> 3, jj = (q & 7) ^ (row & 7);
      cp16(Kbh + (size_t)(s0 + row) * 64 + jj * 8, U + (p * 256 + (tid & ~63)) * 8);
    }
    // stage V^T tile [64][128] manually (swizzle16)
#pragma unroll
    for (int p = 0; p < 4; ++p) {
      int q = p * 256 + tid;
      int d = q >> 4, sc = q & 15;
      uint4 v = *(const uint4*)(Vtbh + (size_t)d * 1024 + s0 + sc * 8);
      *(uint4*)&Vts[d * 128 + (sc ^ (d & 15)) * 8] = v;
    }
    __syncthreads();

    // ---- QK^T: S^T[s][t] = K.Q^T ----
    f32x4 accp[4][4];
    for (int i = 0; i < 4; ++i)
      for (int j = 0; j < 4; ++j) accp[i][j] = zero;
#pragma unroll
    for (int kk = 0; kk < 2; ++kk) {
      bf16x8 af[4], bf[4];
#pragma unroll
      for (int mt = 0; mt < 4; ++mt) {
        int row = wr * 64 + mt * 16 + c;  // s_local
        af[mt] = *(const bf16x8*)(U + row * 64 + (((kk << 2) + quad) ^ (c & 7)) * 8);
      }
#pragma unroll
      for (int nt = 0; nt < 4; ++nt) {
        int row = wc * 64 + nt * 16 + c;  // t_local
        bf[nt] = *(const bf16x8*)(Qs + row * 64 + (((kk << 2) + quad) ^ (c & 7)) * 8);
      }
#pragma unroll
      for (int mt = 0; mt < 4; ++mt)
#pragma unroll
        for (int nt = 0; nt < 4; ++nt)
          accp[mt][nt] = __builtin_amdgcn_mfma_f32_16x16x32_bf16(
              af[mt], bf[nt], accp[mt][nt], 0, 0, 0);
    }

    // ---- sigmoid + store attn f32 (lane holds 4 consecutive s at fixed t) ----
#pragma unroll
    for (int mt = 0; mt < 4; ++mt) {
      int sl = wr * 64 + mt * 16 + quad * 4;
#pragma unroll
      for (int nt = 0; nt < 4; ++nt) {
        int t = wc * 64 + nt * 16 + c;
        f32x4 pv;
#pragma unroll
        for (int r = 0; r < 4; ++r)
          pv[r] = 1.0f / (1.0f + __expf(-accp[mt][nt][r]));
        accp[mt][nt] = pv;
        *(f32x4*)(attnb + (size_t)(t0 + t) * 1024 + s0 + sl) = pv;
      }
    }
    __syncthreads();  // all waves done reading Ks region of U

    // ---- write P bf16 into U as Ps[t][s], swizzle16, 8B packed ----
#pragma unroll
    for (int mt = 0; mt < 4; ++mt) {
      int sbase = wr * 64 + mt * 16 + quad * 4;
      int jw = sbase >> 3, hf = (sbase >> 2) & 1;
#pragma unroll
      for (int nt = 0; nt < 4; ++nt) {
        int t = wc * 64 + nt * 16 + c;
        int jj = jw ^ (t & 15);
        uint2 pk;
        pk.x = (uint32_t)f2bf(accp[mt][nt][0]) | ((uint32_t)f2bf(accp[mt][nt][1]) << 16);
        pk.y = (uint32_t)f2bf(accp[mt][nt][2]) | ((uint32_t)f2bf(accp[mt][nt][3]) << 16);
        *(uint2*)&U[t * 128 + jj * 8 + hf * 4] = pk;
      }
    }
    __syncthreads();

    // ---- PV: O[t][d] += P[t][s] * V[s][d] ----
#pragma unroll
    for (int kk = 0; kk < 4; ++kk) {
      bf16x8 ap[2], bv[4];
#pragma unroll
      for (int mt = 0; mt < 2; ++mt) {
        int row = w * 32 + mt * 16 + c;  // t_local
        ap[mt] = *(const bf16x8*)(U + row * 128 + (((kk << 2) + quad) ^ (row & 15)) * 8);
      }
#pragma unroll
      for (int nt = 0; nt < 4; ++nt) {
        int d = nt * 16 + c;
        bv[nt] = *(const bf16x8*)(Vts + d * 128 + (((kk << 2) + quad) ^ (d & 15)) * 8);
      }
#pragma unroll
      for (int mt = 0; mt < 2; ++mt)
#pragma unroll
        for (int nt = 0; nt < 4; ++nt)
          acc_o[mt][nt] = __builtin_amdgcn_mfma_f32_16x16x32_bf16(
              ap[mt], bv[nt], acc_o[mt][nt], 0, 0, 0);
    }
  }

  // ---- epilogue: AO[(t*4+b)*1024 + h*64 + d] (bf16) ----
#pragma unroll
  for (int mt = 0; mt < 2; ++mt)
#pragma unroll
    for (int nt = 0; nt < 4; ++nt) {
      int d = nt * 16 + c;
#pragma unroll
      for (int r = 0; r < 4; ++r) {
        int t = t0 + w * 32 + mt * 16 + quad * 4 + r;
        AO[(size_t)(t * 4 + b) * 1024 + h * 64 + d] = f2bf(acc_o[mt][nt][r]);
      }
    }
}

// ---------- launch ----------
extern "C" void kernel_launch(void* const* d_in, const int* in_sizes, int n_in,
                              void* d_out, int out_size, void* d_ws, size_t ws_size,
                              hipStream_t stream) {
  const float* query = (const float*)d_in[0];
  const float* key = (const float*)d_in[1];
  const float* value = (const float*)d_in[2];
  const float* in_w = (const float*)d_in[3];
  const float* in_b = (const float*)d_in[4];
  const float* out_w = (const float*)d_in[5];
  const float* out_b = (const float*)d_in[6];
  float* out = (float*)d_out;

  u16* ws = (u16*)d_ws;
  u16* xq = ws;                    // 3 x 4096x1024 (q,k,v inputs bf16)
  u16* win = ws + 12582912;        // 3072x1024
  u16* wout = ws + 15728640;       // 1024x1024
  u16* Qp = ws + 16777216;         // [bh][t][d]
  u16* Kp = ws + 20971520;         // [bh][s][d]
  u16* Vt = ws + 25165824;         // [bh][d][s]
  u16* Vtmp = ws + 29360128;       // [bh][s][d]
  u16* AO = ws + 33554432;         // [(t*4+b)][e]

  cvt_kernel<<<4096, 256, 0, stream>>>(query, xq, 1048576);
  cvt_kernel<<<4096, 256, 0, stream>>>(key, xq + 4194304, 1048576);
  cvt_kernel<<<4096, 256, 0, stream>>>(value, xq + 8388608, 1048576);
  cvt_kernel<<<3072, 256, 0, stream>>>(in_w, win, 786432);
  cvt_kernel<<<1024, 256, 0, stream>>>(out_w, wout, 262144);

  proj_kernel<<<dim3(8, 32, 3), 256, 0, stream>>>(xq, win, in_b, Qp, Kp, Vtmp);
  transpose_v<<<dim3(16, 64), 256, 0, stream>>>(Vtmp, Vt);
  attn_kernel<<<dim3(8, 64), 256, 0, stream>>>(Qp, Kp, Vt, out + 4194304, AO);
  outproj_kernel<<<dim3(8, 32), 256, 0, stream>>>(AO, wout, out_b, out);
}

// Round 2
// 470.519 us; speedup vs baseline: 1.0317x; 1.0317x over previous
//
#include <hip/hip_runtime.h>
#include <stdint.h>

typedef unsigned short u16;
typedef __bf16 bf16x8 __attribute__((ext_vector_type(8)));
typedef float f32x4 __attribute__((ext_vector_type(4)));

// ---------- helpers ----------
__device__ __forceinline__ u16 f2bf(float f) {
  union { float f; uint32_t u; } v; v.f = f;
  uint32_t u = v.u;
  return (u16)((u + 0x7FFFu + ((u >> 16) & 1u)) >> 16);  // RNE
}

__device__ __forceinline__ float fast_sigmoid(float x) {
  // 1/(1+exp(-x)) = rcp(1 + exp2(-x*log2e)); native exp2 + rcp (~1ulp each)
  float e = __builtin_amdgcn_exp2f(x * -1.4426950408889634f);
  return __builtin_amdgcn_rcpf(1.0f + e);
}

// async global->LDS, 16B per lane. LDS dest = wave-uniform base + lane*16.
__device__ __forceinline__ void cp16(const void* g, void* lds) {
  __builtin_amdgcn_global_load_lds(
      (const __attribute__((address_space(1))) uint32_t*)(uintptr_t)g,
      (__attribute__((address_space(3))) uint32_t*)(uint32_t)(uintptr_t)lds,
      16, 0, 0);
}

// ---------- merged f32 -> bf16 conversion over all 5 inputs ----------
// regions (float4 units, all multiples of 256 so branches are block-uniform):
// q [0,1048576) k [..2097152) v [..3145728) iw [..3932160) ow [..4194304)
__global__ __launch_bounds__(256) void cvt_all(
    const float* __restrict__ q, const float* __restrict__ k,
    const float* __restrict__ v, const float* __restrict__ iw,
    const float* __restrict__ ow, u16* __restrict__ xq,
    u16* __restrict__ win, u16* __restrict__ wout) {
  int i = blockIdx.x * 256 + threadIdx.x;
  const float* s;
  u16* d;
  int off;
  if (i < 2097152) {
    if (i < 1048576) { s = q; d = xq; off = i; }
    else { s = k; d = xq + 4194304; off = i - 1048576; }
  } else if (i < 3145728) { s = v; d = xq + 8388608; off = i - 2097152; }
  else if (i < 3932160) { s = iw; d = win; off = i - 3145728; }
  else { s = ow; d = wout; off = i - 3932160; }
  float4 f = ((const float4*)s)[off];
  uint2 p;
  p.x = (uint32_t)f2bf(f.x) | ((uint32_t)f2bf(f.y) << 16);
  p.y = (uint32_t)f2bf(f.z) | ((uint32_t)f2bf(f.w) << 16);
  ((uint2*)d)[off] = p;
}

// ---------- shared 128x128 GEMM mainloop (A[M,K] x Bt[N,K], bf16, K%64==0) ----------
__device__ __forceinline__ void gemm128(const u16* __restrict__ A,
                                        const u16* __restrict__ Bt,
                                        int m0, int n0, int K,
                                        u16* As, u16* Bs, f32x4 acc[4][4]) {
  const int tid = threadIdx.x;
  const int l = tid & 63, w = tid >> 6;
  const int wr = w >> 1, wc = w & 1;
  const int quad = l >> 4, c = l & 15;
  const f32x4 zero = {0.f, 0.f, 0.f, 0.f};
  for (int i = 0; i < 4; ++i)
    for (int j = 0; j < 4; ++j) acc[i][j] = zero;

  for (int k0 = 0; k0 < K; k0 += 64) {
    __syncthreads();
#pragma unroll
    for (int p = 0; p < 4; ++p) {
      int q = p * 256 + tid;
      int row = q >> 3;
      int jj = (q & 7) ^ (row & 7);
      int ldsbase = (p * 256 + (tid & ~63)) * 8;
      cp16(A + (size_t)(m0 + row) * K + k0 + jj * 8, As + ldsbase);
      cp16(Bt + (size_t)(n0 + row) * K + k0 + jj * 8, Bs + ldsbase);
    }
    __syncthreads();
#pragma unroll
    for (int kk = 0; kk < 2; ++kk) {
      bf16x8 af[4], bf[4];
#pragma unroll
      for (int mt = 0; mt < 4; ++mt) {
        int row = wr * 64 + mt * 16 + c;
        af[mt] = *(const bf16x8*)(As + row * 64 + ((((kk << 2) + quad)) ^ (c & 7)) * 8);
      }
#pragma unroll
      for (int nt = 0; nt < 4; ++nt) {
        int row = wc * 64 + nt * 16 + c;
        bf[nt] = *(const bf16x8*)(Bs + row * 64 + ((((kk << 2) + quad)) ^ (c & 7)) * 8);
      }
#pragma unroll
      for (int mt = 0; mt < 4; ++mt)
#pragma unroll
        for (int nt = 0; nt < 4; ++nt)
          acc[mt][nt] = __builtin_amdgcn_mfma_f32_16x16x32_bf16(
              af[mt], bf[nt], acc[mt][nt], 0, 0, 0);
    }
  }
}

// ---------- QKV projection ----------
__global__ __launch_bounds__(256, 2) void proj_kernel(
    const u16* __restrict__ X, const u16* __restrict__ Win,
    const float* __restrict__ in_bias, u16* __restrict__ Q,
    u16* __restrict__ Kp, u16* __restrict__ Vtmp) {
  __shared__ u16 As[8192], Bs[8192];
  const int which = blockIdx.z;
  const u16* A = X + (size_t)which * (4096 * 1024);
  const u16* Bt = Win + (size_t)which * (1024 * 1024);
  const int m0 = blockIdx.y * 128, n0 = blockIdx.x * 128;
  f32x4 acc[4][4];
  gemm128(A, Bt, m0, n0, 1024, As, Bs, acc);

  u16* dst = (which == 0) ? Q : ((which == 1) ? Kp : Vtmp);
  const float scale = (which == 0) ? 0.03125f : 1.0f;  // q /= sqrt(1024)
  const float* bias = in_bias + which * 1024;
  const int l = threadIdx.x & 63, w = threadIdx.x >> 6;
  const int wr = w >> 1, wc = w & 1, quad = l >> 4, c = l & 15;
#pragma unroll
  for (int mt = 0; mt < 4; ++mt)
#pragma unroll
    for (int nt = 0; nt < 4; ++nt) {
      int n = n0 + wc * 64 + nt * 16 + c;
      float bv = bias[n];
      int h = n >> 6, d = n & 63;
#pragma unroll
      for (int r = 0; r < 4; ++r) {
        int m = m0 + wr * 64 + mt * 16 + quad * 4 + r;
        int t = m >> 2, b = m & 3;
        dst[((size_t)((b * 16 + h) * 1024 + t)) * 64 + d] =
            f2bf((acc[mt][nt][r] + bv) * scale);
      }
    }
}

// ---------- out projection -> f32 (nontemporal) ----------
__global__ __launch_bounds__(256, 2) void outproj_kernel(
    const u16* __restrict__ AO, const u16* __restrict__ Wout,
    const float* __restrict__ out_bias, float* __restrict__ out) {
  __shared__ u16 As[8192], Bs[8192];
  const int m0 = blockIdx.y * 128, n0 = blockIdx.x * 128;
  f32x4 acc[4][4];
  gemm128(AO, Wout, m0, n0, 1024, As, Bs, acc);
  const int l = threadIdx.x & 63, w = threadIdx.x >> 6;
  const int wr = w >> 1, wc = w & 1, quad = l >> 4, c = l & 15;
#pragma unroll
  for (int mt = 0; mt < 4; ++mt)
#pragma unroll
    for (int nt = 0; nt < 4; ++nt) {
      int n = n0 + wc * 64 + nt * 16 + c;
      float bv = out_bias[n];
#pragma unroll
      for (int r = 0; r < 4; ++r) {
        int m = m0 + wr * 64 + mt * 16 + quad * 4 + r;
        __builtin_nontemporal_store(acc[mt][nt][r] + bv, &out[(size_t)m * 1024 + n]);
      }
    }
}

// ---------- V transpose: Vtmp[bh][s][d] -> Vt[bh][d][s] ----------
__global__ __launch_bounds__(256) void transpose_v(const u16* __restrict__ Vtmp,
                                                   u16* __restrict__ Vt) {
  __shared__ u16 tile[64 * 72];
  const int bh = blockIdx.y, s0 = blockIdx.x * 64;
  const u16* src = Vtmp + (size_t)bh * 65536;
  u16* dst = Vt + (size_t)bh * 65536;
#pragma unroll
  for (int p = 0; p < 2; ++p) {
    int q = p * 256 + threadIdx.x;
    int sl = q >> 3, dc = q & 7;
    uint4 v = *(const uint4*)(src + (size_t)(s0 + sl) * 64 + dc * 8);
    *(uint4*)&tile[sl * 72 + dc * 8] = v;
  }
  __syncthreads();
#pragma unroll
  for (int p = 0; p < 2; ++p) {
    int q = p * 256 + threadIdx.x;
    int d = q >> 3, sc = q & 7;
    u16 vals[8] __attribute__((aligned(16)));
#pragma unroll
    for (int j = 0; j < 8; ++j) vals[j] = tile[(sc * 8 + j) * 72 + d];
    *(uint4*)(dst + (size_t)d * 1024 + s0 + sc * 8) = *(const uint4*)vals;
  }
}

// ---------- fused attention: P = sigmoid(K.Q^T), O += P.V ----------
// Dynamic LDS 80KB: Qs 16K | Ks 16K | Vts 16K | Ps 32K  -> 2 blocks/CU (160K).
// 3 barriers/iter (Ps separate from Ks removes the pack-overwrite barrier).
__global__ __launch_bounds__(256, 2) void attn_kernel(
    const u16* __restrict__ Q, const u16* __restrict__ Kg,
    const u16* __restrict__ Vt, float* __restrict__ attn_out,
    u16* __restrict__ AO) {
  extern __shared__ u16 smem[];
  u16* Qs = smem;            // [t 128][d 64], swizzle8
  u16* Ks = smem + 8192;     // [s 128][d 64], swizzle8
  u16* Vts = smem + 16384;   // [d 64][s 128], swizzle16
  u16* Ps = smem + 24576;    // [t 128][s 128], swizzle16
  const int bh = blockIdx.y, t0 = blockIdx.x * 128;
  const int b = bh >> 4, h = bh & 15;
  const int tid = threadIdx.x, l = tid & 63, w = tid >> 6;
  const int quad = l >> 4, c = l & 15;
  const int wr = w >> 1, wc = w & 1;
  const u16* Qbh = Q + (size_t)bh * 65536;
  const u16* Kbh = Kg + (size_t)bh * 65536;
  const u16* Vtbh = Vt + (size_t)bh * 65536;
  float* attnb = attn_out + (size_t)bh * 1048576;

  // stage Q tile once
#pragma unroll
  for (int p = 0; p < 4; ++p) {
    int q = p * 256 + tid;
    int row = q >> 3, jj = (q & 7) ^ (row & 7);
    cp16(Qbh + (size_t)(t0 + row) * 64 + jj * 8, Qs + (p * 256 + (tid & ~63)) * 8);
  }

  const f32x4 zero = {0.f, 0.f, 0.f, 0.f};
  f32x4 acc_o[2][4];
  for (int i = 0; i < 2; ++i)
    for (int j = 0; j < 4; ++j) acc_o[i][j] = zero;

  for (int s0 = 0; s0 < 1024; s0 += 128) {
    __syncthreads();  // (a) prev-iter readers of Ks/Vts/Ps done; Q/attn stores drain
    // stage K tile
#pragma unroll
    for (int p = 0; p < 4; ++p) {
      int q = p * 256 + tid;
      int row = q >> 3, jj = (q & 7) ^ (row & 7);
      cp16(Kbh + (size_t)(s0 + row) * 64 + jj * 8, Ks + (p * 256 + (tid & ~63)) * 8);
    }
    // stage V^T tile [64][128] manually (swizzle16)
#pragma unroll
    for (int p = 0; p < 4; ++p) {
      int q = p * 256 + tid;
      int d = q >> 4, sc = q & 15;
      uint4 v = *(const uint4*)(Vtbh + (size_t)d * 1024 + s0 + sc * 8);
      *(uint4*)&Vts[d * 128 + (sc ^ (d & 15)) * 8] = v;
    }
    __syncthreads();  // (b) tiles visible

    // ---- QK^T: S^T[s][t] = K.Q^T ----
    f32x4 accp[4][4];
    for (int i = 0; i < 4; ++i)
      for (int j = 0; j < 4; ++j) accp[i][j] = zero;
#pragma unroll
    for (int kk = 0; kk < 2; ++kk) {
      bf16x8 af[4], bf[4];
#pragma unroll
      for (int mt = 0; mt < 4; ++mt) {
        int row = wr * 64 + mt * 16 + c;  // s_local
        af[mt] = *(const bf16x8*)(Ks + row * 64 + (((kk << 2) + quad) ^ (c & 7)) * 8);
      }
#pragma unroll
      for (int nt = 0; nt < 4; ++nt) {
        int row = wc * 64 + nt * 16 + c;  // t_local
        bf[nt] = *(const bf16x8*)(Qs + row * 64 + (((kk << 2) + quad) ^ (c & 7)) * 8);
      }
#pragma unroll
      for (int mt = 0; mt < 4; ++mt)
#pragma unroll
        for (int nt = 0; nt < 4; ++nt)
          accp[mt][nt] = __builtin_amdgcn_mfma_f32_16x16x32_bf16(
              af[mt], bf[nt], accp[mt][nt], 0, 0, 0);
    }

    // ---- sigmoid + pack P bf16 into Ps[t][s] (swizzle16, 8B stores) ----
#pragma unroll
    for (int mt = 0; mt < 4; ++mt) {
      int sbase = wr * 64 + mt * 16 + quad * 4;
      int jw = sbase >> 3, hf = (sbase >> 2) & 1;
#pragma unroll
      for (int nt = 0; nt < 4; ++nt) {
        int t = wc * 64 + nt * 16 + c;
        f32x4 pv;
#pragma unroll
        for (int r = 0; r < 4; ++r) pv[r] = fast_sigmoid(accp[mt][nt][r]);
        accp[mt][nt] = pv;
        int jj = jw ^ (t & 15);
        uint2 pk;
        pk.x = (uint32_t)f2bf(pv[0]) | ((uint32_t)f2bf(pv[1]) << 16);
        pk.y = (uint32_t)f2bf(pv[2]) | ((uint32_t)f2bf(pv[3]) << 16);
        *(uint2*)&Ps[t * 128 + jj * 8 + hf * 4] = pk;
      }
    }
    __syncthreads();  // (c) Ps visible

    // ---- attn f32 stores AFTER the barrier: drain overlaps PV MFMAs ----
#pragma unroll
    for (int mt = 0; mt < 4; ++mt) {
      int sl = wr * 64 + mt * 16 + quad * 4;
#pragma unroll
      for (int nt = 0; nt < 4; ++nt) {
        int t = wc * 64 + nt * 16 + c;
        __builtin_nontemporal_store(
            accp[mt][nt], (f32x4*)(attnb + (size_t)(t0 + t) * 1024 + s0 + sl));
      }
    }

    // ---- PV: O[t][d] += P[t][s] * V[s][d] ----
#pragma unroll
    for (int kk = 0; kk < 4; ++kk) {
      bf16x8 ap[2], bv[4];
#pragma unroll
      for (int mt = 0; mt < 2; ++mt) {
        int row = w * 32 + mt * 16 + c;  // t_local
        ap[mt] = *(const bf16x8*)(Ps + row * 128 + (((kk << 2) + quad) ^ (row & 15)) * 8);
      }
#pragma unroll
      for (int nt = 0; nt < 4; ++nt) {
        int d = nt * 16 + c;
        bv[nt] = *(const bf16x8*)(Vts + d * 128 + (((kk << 2) + quad) ^ (d & 15)) * 8);
      }
#pragma unroll
      for (int mt = 0; mt < 2; ++mt)
#pragma unroll
        for (int nt = 0; nt < 4; ++nt)
          acc_o[mt][nt] = __builtin_amdgcn_mfma_f32_16x16x32_bf16(
              ap[mt], bv[nt], acc_o[mt][nt], 0, 0, 0);
    }
  }

  // ---- epilogue: AO[(t*4+b)*1024 + h*64 + d] (bf16) ----
#pragma unroll
  for (int mt = 0; mt < 2; ++mt)
#pragma unroll
    for (int nt = 0; nt < 4; ++nt) {
      int d = nt * 16 + c;
#pragma unroll
      for (int r = 0; r < 4; ++r) {
        int t = t0 + w * 32 + mt * 16 + quad * 4 + r;
        AO[(size_t)(t * 4 + b) * 1024 + h * 64 + d] = f2bf(acc_o[mt][nt][r]);
      }
    }
}

// ---------- launch ----------
extern "C" void kernel_launch(void* const* d_in, const int* in_sizes, int n_in,
                              void* d_out, int out_size, void* d_ws, size_t ws_size,
                              hipStream_t stream) {
  const float* query = (const float*)d_in[0];
  const float* key = (const float*)d_in[1];
  const float* value = (const float*)d_in[2];
  const float* in_w = (const float*)d_in[3];
  const float* in_b = (const float*)d_in[4];
  const float* out_w = (const float*)d_in[5];
  const float* out_b = (const float*)d_in[6];
  float* out = (float*)d_out;

  u16* ws = (u16*)d_ws;
  u16* xq = ws;                    // 3 x 4096x1024 (q,k,v inputs bf16)
  u16* win = ws + 12582912;        // 3072x1024
  u16* wout = ws + 15728640;       // 1024x1024
  u16* Qp = ws + 16777216;         // [bh][t][d]
  u16* Kp = ws + 20971520;         // [bh][s][d]
  u16* Vt = ws + 25165824;         // [bh][d][s]
  u16* Vtmp = ws + 29360128;       // [bh][s][d]
  u16* AO = ws + 33554432;         // [(t*4+b)][e]

  hipFuncSetAttribute((const void*)attn_kernel,
                      hipFuncAttributeMaxDynamicSharedMemorySize, 81920);

  cvt_all<<<16384, 256, 0, stream>>>(query, key, value, in_w, out_w, xq, win, wout);
  proj_kernel<<<dim3(8, 32, 3), 256, 0, stream>>>(xq, win, in_b, Qp, Kp, Vtmp);
  transpose_v<<<dim3(16, 64), 256, 0, stream>>>(Vtmp, Vt);
  attn_kernel<<<dim3(8, 64), 256, 81920, stream>>>(Qp, Kp, Vt, out + 4194304, AO);
  outproj_kernel<<<dim3(8, 32), 256, 0, stream>>>(AO, wout, out_b, out);
}

// Round 3
// 462.054 us; speedup vs baseline: 1.0506x; 1.0183x over previous
//
#include <hip/hip_runtime.h>
#include <stdint.h>

typedef unsigned short u16;
typedef __bf16 bf16x8 __attribute__((ext_vector_type(8)));
typedef float f32x4 __attribute__((ext_vector_type(4)));

// ---------- helpers ----------
__device__ __forceinline__ u16 f2bf(float f) {
  union { float f; uint32_t u; } v; v.f = f;
  uint32_t u = v.u;
  return (u16)((u + 0x7FFFu + ((u >> 16) & 1u)) >> 16);  // RNE
}

__device__ __forceinline__ float fast_sigmoid(float x) {
  float e = __builtin_amdgcn_exp2f(x * -1.4426950408889634f);
  return __builtin_amdgcn_rcpf(1.0f + e);
}

// async global->LDS, 16B per lane. LDS dest = wave-uniform base + lane*16.
__device__ __forceinline__ void cp16(const void* g, void* lds) {
  __builtin_amdgcn_global_load_lds(
      (const __attribute__((address_space(1))) uint32_t*)(uintptr_t)g,
      (__attribute__((address_space(3))) uint32_t*)(uint32_t)(uintptr_t)lds,
      16, 0, 0);
}

// ---------- merged f32 -> bf16 conversion over all 5 inputs ----------
__global__ __launch_bounds__(256) void cvt_all(
    const float* __restrict__ q, const float* __restrict__ k,
    const float* __restrict__ v, const float* __restrict__ iw,
    const float* __restrict__ ow, u16* __restrict__ xq,
    u16* __restrict__ win, u16* __restrict__ wout) {
  int i = blockIdx.x * 256 + threadIdx.x;
  const float* s;
  u16* d;
  int off;
  if (i < 2097152) {
    if (i < 1048576) { s = q; d = xq; off = i; }
    else { s = k; d = xq + 4194304; off = i - 1048576; }
  } else if (i < 3145728) { s = v; d = xq + 8388608; off = i - 2097152; }
  else if (i < 3932160) { s = iw; d = win; off = i - 3145728; }
  else { s = ow; d = wout; off = i - 3932160; }
  float4 f = ((const float4*)s)[off];
  uint2 p;
  p.x = (uint32_t)f2bf(f.x) | ((uint32_t)f2bf(f.y) << 16);
  p.y = (uint32_t)f2bf(f.z) | ((uint32_t)f2bf(f.w) << 16);
  ((uint2*)d)[off] = p;
}

// ---------- shared 128x128 GEMM mainloop (A[M,K] x Bt[N,K], bf16, K%64==0) ----------
__device__ __forceinline__ void gemm128(const u16* __restrict__ A,
                                        const u16* __restrict__ Bt,
                                        int m0, int n0, int K,
                                        u16* As, u16* Bs, f32x4 acc[4][4]) {
  const int tid = threadIdx.x;
  const int l = tid & 63, w = tid >> 6;
  const int wr = w >> 1, wc = w & 1;
  const int quad = l >> 4, c = l & 15;
  const f32x4 zero = {0.f, 0.f, 0.f, 0.f};
  for (int i = 0; i < 4; ++i)
    for (int j = 0; j < 4; ++j) acc[i][j] = zero;

  for (int k0 = 0; k0 < K; k0 += 64) {
    __syncthreads();
#pragma unroll
    for (int p = 0; p < 4; ++p) {
      int q = p * 256 + tid;
      int row = q >> 3;
      int jj = (q & 7) ^ (row & 7);
      int ldsbase = (p * 256 + (tid & ~63)) * 8;
      cp16(A + (size_t)(m0 + row) * K + k0 + jj * 8, As + ldsbase);
      cp16(Bt + (size_t)(n0 + row) * K + k0 + jj * 8, Bs + ldsbase);
    }
    __syncthreads();
#pragma unroll
    for (int kk = 0; kk < 2; ++kk) {
      bf16x8 af[4], bf[4];
#pragma unroll
      for (int mt = 0; mt < 4; ++mt) {
        int row = wr * 64 + mt * 16 + c;
        af[mt] = *(const bf16x8*)(As + row * 64 + ((((kk << 2) + quad)) ^ (c & 7)) * 8);
      }
#pragma unroll
      for (int nt = 0; nt < 4; ++nt) {
        int row = wc * 64 + nt * 16 + c;
        bf[nt] = *(const bf16x8*)(Bs + row * 64 + ((((kk << 2) + quad)) ^ (c & 7)) * 8);
      }
#pragma unroll
      for (int mt = 0; mt < 4; ++mt)
#pragma unroll
        for (int nt = 0; nt < 4; ++nt)
          acc[mt][nt] = __builtin_amdgcn_mfma_f32_16x16x32_bf16(
              af[mt], bf[nt], acc[mt][nt], 0, 0, 0);
    }
  }
}

// ---------- QKV projection; V written directly transposed ([bh][d][t]) ----------
__global__ __launch_bounds__(256, 2) void proj_kernel(
    const u16* __restrict__ X, const u16* __restrict__ Win,
    const float* __restrict__ in_bias, u16* __restrict__ Q,
    u16* __restrict__ Kp, u16* __restrict__ Vt) {
  __shared__ u16 As[8192], Bs[8192];
  const int which = blockIdx.z;
  const u16* A = X + (size_t)which * (4096 * 1024);
  const u16* Bt = Win + (size_t)which * (1024 * 1024);
  const int m0 = blockIdx.y * 128, n0 = blockIdx.x * 128;
  f32x4 acc[4][4];
  gemm128(A, Bt, m0, n0, 1024, As, Bs, acc);

  const float scale = (which == 0) ? 0.03125f : 1.0f;  // q /= sqrt(1024)
  const float* bias = in_bias + which * 1024;
  const int l = threadIdx.x & 63, w = threadIdx.x >> 6;
  const int wr = w >> 1, wc = w & 1, quad = l >> 4, c = l & 15;
#pragma unroll
  for (int mt = 0; mt < 4; ++mt)
#pragma unroll
    for (int nt = 0; nt < 4; ++nt) {
      int n = n0 + wc * 64 + nt * 16 + c;
      float bv = bias[n];
      int h = n >> 6, d = n & 63;
#pragma unroll
      for (int r = 0; r < 4; ++r) {
        int m = m0 + wr * 64 + mt * 16 + quad * 4 + r;
        int t = m >> 2, b = m & 3;
        u16 val = f2bf((acc[mt][nt][r] + bv) * scale);
        if (which == 2) {
          // Vt[bh][d][t] — block covers t-range of exactly 32 (full 64B lines via L2)
          Vt[((size_t)(b * 16 + h) * 64 + d) * 1024 + t] = val;
        } else {
          u16* dst = (which == 0) ? Q : Kp;
          dst[((size_t)((b * 16 + h) * 1024 + t)) * 64 + d] = val;
        }
      }
    }
}

// ---------- out projection, 128x64 tiles (512 blocks -> 2 blocks/CU) ----------
__global__ __launch_bounds__(256, 2) void outproj_kernel(
    const u16* __restrict__ AO, const u16* __restrict__ Wout,
    const float* __restrict__ out_bias, float* __restrict__ out) {
  __shared__ u16 As[8192];  // [128 m][64 k] swizzle8
  __shared__ u16 Bs[4096];  // [64 n][64 k] swizzle8
  const int m0 = blockIdx.y * 128, n0 = blockIdx.x * 64;
  const int tid = threadIdx.x, l = tid & 63, w = tid >> 6;
  const int quad = l >> 4, c = l & 15;
  const f32x4 zero = {0.f, 0.f, 0.f, 0.f};
  f32x4 acc[2][4];
  for (int i = 0; i < 2; ++i)
    for (int j = 0; j < 4; ++j) acc[i][j] = zero;

  for (int k0 = 0; k0 < 1024; k0 += 64) {
    __syncthreads();
#pragma unroll
    for (int p = 0; p < 4; ++p) {
      int q = p * 256 + tid;
      int row = q >> 3, jj = (q & 7) ^ (row & 7);
      cp16(AO + (size_t)(m0 + row) * 1024 + k0 + jj * 8,
           As + (p * 256 + (tid & ~63)) * 8);
    }
#pragma unroll
    for (int p = 0; p < 2; ++p) {
      int q = p * 256 + tid;
      int row = q >> 3, jj = (q & 7) ^ (row & 7);
      cp16(Wout + (size_t)(n0 + row) * 1024 + k0 + jj * 8,
           Bs + (p * 256 + (tid & ~63)) * 8);
    }
    __syncthreads();
#pragma unroll
    for (int kk = 0; kk < 2; ++kk) {
      bf16x8 af[2], bf[4];
#pragma unroll
      for (int mt = 0; mt < 2; ++mt) {
        int row = w * 32 + mt * 16 + c;
        af[mt] = *(const bf16x8*)(As + row * 64 + (((kk << 2) + quad) ^ (c & 7)) * 8);
      }
#pragma unroll
      for (int nt = 0; nt < 4; ++nt) {
        int row = nt * 16 + c;
        bf[nt] = *(const bf16x8*)(Bs + row * 64 + (((kk << 2) + quad) ^ (c & 7)) * 8);
      }
#pragma unroll
      for (int mt = 0; mt < 2; ++mt)
#pragma unroll
        for (int nt = 0; nt < 4; ++nt)
          acc[mt][nt] = __builtin_amdgcn_mfma_f32_16x16x32_bf16(
              af[mt], bf[nt], acc[mt][nt], 0, 0, 0);
    }
  }
#pragma unroll
  for (int mt = 0; mt < 2; ++mt)
#pragma unroll
    for (int nt = 0; nt < 4; ++nt) {
      int n = n0 + nt * 16 + c;
      float bv = out_bias[n];
#pragma unroll
      for (int r = 0; r < 4; ++r) {
        int m = m0 + w * 32 + mt * 16 + quad * 4 + r;
        __builtin_nontemporal_store(acc[mt][nt][r] + bv, &out[(size_t)m * 1024 + n]);
      }
    }
}

// ---------- fused attention: P = sigmoid(K.Q^T), O += P.V ----------
// Dynamic LDS 80KB: Qs 16K | Ks 16K | Vts 16K | Ps 32K  -> 2 blocks/CU (160K).
__global__ __launch_bounds__(256, 2) void attn_kernel(
    const u16* __restrict__ Q, const u16* __restrict__ Kg,
    const u16* __restrict__ Vt, float* __restrict__ attn_out,
    u16* __restrict__ AO) {
  extern __shared__ u16 smem[];
  u16* Qs = smem;            // [t 128][d 64], swizzle8
  u16* Ks = smem + 8192;     // [s 128][d 64], swizzle8
  u16* Vts = smem + 16384;   // [d 64][s 128], swizzle16
  u16* Ps = smem + 24576;    // [t 128][s 128], swizzle16
  const int bh = blockIdx.y, t0 = blockIdx.x * 128;
  const int b = bh >> 4, h = bh & 15;
  const int tid = threadIdx.x, l = tid & 63, w = tid >> 6;
  const int quad = l >> 4, c = l & 15;
  const int wr = w >> 1, wc = w & 1;
  const u16* Qbh = Q + (size_t)bh * 65536;
  const u16* Kbh = Kg + (size_t)bh * 65536;
  const u16* Vtbh = Vt + (size_t)bh * 65536;
  float* attnb = attn_out + (size_t)bh * 1048576;

  // stage Q tile once
#pragma unroll
  for (int p = 0; p < 4; ++p) {
    int q = p * 256 + tid;
    int row = q >> 3, jj = (q & 7) ^ (row & 7);
    cp16(Qbh + (size_t)(t0 + row) * 64 + jj * 8, Qs + (p * 256 + (tid & ~63)) * 8);
  }

  const f32x4 zero = {0.f, 0.f, 0.f, 0.f};
  f32x4 acc_o[2][4];
  for (int i = 0; i < 2; ++i)
    for (int j = 0; j < 4; ++j) acc_o[i][j] = zero;

  for (int s0 = 0; s0 < 1024; s0 += 128) {
    __syncthreads();  // (a) prev-iter readers done; store queue drains
#pragma unroll
    for (int p = 0; p < 4; ++p) {
      int q = p * 256 + tid;
      int row = q >> 3, jj = (q & 7) ^ (row & 7);
      cp16(Kbh + (size_t)(s0 + row) * 64 + jj * 8, Ks + (p * 256 + (tid & ~63)) * 8);
    }
#pragma unroll
    for (int p = 0; p < 4; ++p) {
      int q = p * 256 + tid;
      int d = q >> 4, sc = q & 15;
      uint4 v = *(const uint4*)(Vtbh + (size_t)d * 1024 + s0 + sc * 8);
      *(uint4*)&Vts[d * 128 + (sc ^ (d & 15)) * 8] = v;
    }
    __syncthreads();  // (b) tiles visible

    // ---- QK^T: S^T[s][t] = K.Q^T ----
    f32x4 accp[4][4];
    for (int i = 0; i < 4; ++i)
      for (int j = 0; j < 4; ++j) accp[i][j] = zero;
#pragma unroll
    for (int kk = 0; kk < 2; ++kk) {
      bf16x8 af[4], bf[4];
#pragma unroll
      for (int mt = 0; mt < 4; ++mt) {
        int row = wr * 64 + mt * 16 + c;  // s_local
        af[mt] = *(const bf16x8*)(Ks + row * 64 + (((kk << 2) + quad) ^ (c & 7)) * 8);
      }
#pragma unroll
      for (int nt = 0; nt < 4; ++nt) {
        int row = wc * 64 + nt * 16 + c;  // t_local
        bf[nt] = *(const bf16x8*)(Qs + row * 64 + (((kk << 2) + quad) ^ (c & 7)) * 8);
      }
#pragma unroll
      for (int mt = 0; mt < 4; ++mt)
#pragma unroll
        for (int nt = 0; nt < 4; ++nt)
          accp[mt][nt] = __builtin_amdgcn_mfma_f32_16x16x32_bf16(
              af[mt], bf[nt], accp[mt][nt], 0, 0, 0);
    }

    // ---- sigmoid + pack P bf16 into Ps[t][s] (swizzle16, 8B stores) ----
#pragma unroll
    for (int mt = 0; mt < 4; ++mt) {
      int sbase = wr * 64 + mt * 16 + quad * 4;
      int jw = sbase >> 3, hf = (sbase >> 2) & 1;
#pragma unroll
      for (int nt = 0; nt < 4; ++nt) {
        int t = wc * 64 + nt * 16 + c;
        f32x4 pv;
#pragma unroll
        for (int r = 0; r < 4; ++r) pv[r] = fast_sigmoid(accp[mt][nt][r]);
        accp[mt][nt] = pv;
        int jj = jw ^ (t & 15);
        uint2 pk;
        pk.x = (uint32_t)f2bf(pv[0]) | ((uint32_t)f2bf(pv[1]) << 16);
        pk.y = (uint32_t)f2bf(pv[2]) | ((uint32_t)f2bf(pv[3]) << 16);
        *(uint2*)&Ps[t * 128 + jj * 8 + hf * 4] = pk;
      }
    }
    __syncthreads();  // (c) Ps visible

    // ---- attn f32 stores AFTER the barrier: drain overlaps PV MFMAs ----
#pragma unroll
    for (int mt = 0; mt < 4; ++mt) {
      int sl = wr * 64 + mt * 16 + quad * 4;
#pragma unroll
      for (int nt = 0; nt < 4; ++nt) {
        int t = wc * 64 + nt * 16 + c;
        __builtin_nontemporal_store(
            accp[mt][nt], (f32x4*)(attnb + (size_t)(t0 + t) * 1024 + s0 + sl));
      }
    }

    // ---- PV: O[t][d] += P[t][s] * V[s][d] ----
#pragma unroll
    for (int kk = 0; kk < 4; ++kk) {
      bf16x8 ap[2], bv[4];
#pragma unroll
      for (int mt = 0; mt < 2; ++mt) {
        int row = w * 32 + mt * 16 + c;  // t_local
        ap[mt] = *(const bf16x8*)(Ps + row * 128 + (((kk << 2) + quad) ^ (row & 15)) * 8);
      }
#pragma unroll
      for (int nt = 0; nt < 4; ++nt) {
        int d = nt * 16 + c;
        bv[nt] = *(const bf16x8*)(Vts + d * 128 + (((kk << 2) + quad) ^ (d & 15)) * 8);
      }
#pragma unroll
      for (int mt = 0; mt < 2; ++mt)
#pragma unroll
        for (int nt = 0; nt < 4; ++nt)
          acc_o[mt][nt] = __builtin_amdgcn_mfma_f32_16x16x32_bf16(
              ap[mt], bv[nt], acc_o[mt][nt], 0, 0, 0);
    }
  }

  // ---- epilogue: AO[(t*4+b)*1024 + h*64 + d] (bf16) ----
#pragma unroll
  for (int mt = 0; mt < 2; ++mt)
#pragma unroll
    for (int nt = 0; nt < 4; ++nt) {
      int d = nt * 16 + c;
#pragma unroll
      for (int r = 0; r < 4; ++r) {
        int t = t0 + w * 32 + mt * 16 + quad * 4 + r;
        AO[(size_t)(t * 4 + b) * 1024 + h * 64 + d] = f2bf(acc_o[mt][nt][r]);
      }
    }
}

// ---------- launch ----------
extern "C" void kernel_launch(void* const* d_in, const int* in_sizes, int n_in,
                              void* d_out, int out_size, void* d_ws, size_t ws_size,
                              hipStream_t stream) {
  const float* query = (const float*)d_in[0];
  const float* key = (const float*)d_in[1];
  const float* value = (const float*)d_in[2];
  const float* in_w = (const float*)d_in[3];
  const float* in_b = (const float*)d_in[4];
  const float* out_w = (const float*)d_in[5];
  const float* out_b = (const float*)d_in[6];
  float* out = (float*)d_out;

  u16* ws = (u16*)d_ws;
  u16* xq = ws;                    // 3 x 4096x1024 (q,k,v inputs bf16)
  u16* win = ws + 12582912;        // 3072x1024
  u16* wout = ws + 15728640;       // 1024x1024
  u16* Qp = ws + 16777216;         // [bh][t][d]
  u16* Kp = ws + 20971520;         // [bh][s][d]
  u16* Vt = ws + 25165824;         // [bh][d][s]
  u16* AO = ws + 33554432;         // [(t*4+b)][e]

  hipFuncSetAttribute((const void*)attn_kernel,
                      hipFuncAttributeMaxDynamicSharedMemorySize, 81920);

  cvt_all<<<16384, 256, 0, stream>>>(query, key, value, in_w, out_w, xq, win, wout);
  proj_kernel<<<dim3(8, 32, 3), 256, 0, stream>>>(xq, win, in_b, Qp, Kp, Vt);
  attn_kernel<<<dim3(8, 64), 256, 81920, stream>>>(Qp, Kp, Vt, out + 4194304, AO);
  outproj_kernel<<<dim3(16, 32), 256, 0, stream>>>(AO, wout, out_b, out);
}